// Round 7
// baseline (280.480 us; speedup 1.0000x reference)
//
#include <hip/hip_runtime.h>

// SGC collapsed: out[g] = b2 + sum_{n in g}(dis_n*u1_n + b1.W2)
//                        + sum_{r->c} dis_c * u1_r          (hop2 fused w/ pool)
// v = W1@W2 (75), y0 = x.v, u0 = dis*y0, u1 = dis^2*(S1+u0), S1[c]=sum u0[r].
// 4 kernels (R6 lesson: grid.sync ~37us each on 8 XCDs -> use kernel
// boundaries as barriers; R4/5 lesson: fewer, fatter kernels):
//  K1 partition+y0+init | K2 deg scatter (+dis/u0 tail) |
//  K3 hop1 scatter (+u1 tail) | K4 hop2+pool.
// Tails use the canonical threadfence + atomic-counter last-block pattern
// (device-scope fences, only 16 tail blocks pay the L2 inv).

#define N_    50000
#define E_    800000
#define G_    512
#define F_    75
#define H_    128
#define RR    16         // col ranges
#define BW_   3125       // nodes per range
#define SLOT  288        // per (range, partition-block) slot cap (mean 195)
#define PBLK  256        // partition blocks
#define EPB   3125       // edges per partition block
#define CP    16         // chunk blocks per range in scatter
#define POOLB 128
#define NB    196        // nodes per K1 block (ceil(N_/256))

struct Pr {
    const float* x; const int* row; const int* col; const int* batch;
    const float* W1; const float* b1; const float* W2; const float* b2;
    float* u; float2* kd; float* partial; int* bcnt; int* cnt2; int* cnt3;
    float* cbw; int* bcol; int* brow; float* out;
};

// ---------- K1: v (per block), partition edges, y0 = x.v, init out/cnt/cb ----
__global__ __launch_bounds__(1024)
void k1_part(Pr p) {
    const int t = threadIdx.x, b = blockIdx.x;
    __shared__ float sv[F_ + 1];
    __shared__ int ic[32];
    if (t < 16) ic[t] = 0;
    if (t < F_) {
        float s = 0.f;
        #pragma unroll 8
        for (int j = 0; j < H_; ++j) s += p.W1[t * H_ + j] * p.W2[j];
        sv[t] = s;
    }
    __syncthreads();
    const int e0 = b * EPB;
    for (int e = e0 + t; e < e0 + EPB; e += 1024)
        atomicAdd(&ic[p.col[e] / BW_], 1);
    __syncthreads();
    if (t < 16) {
        int c = ic[t]; if (c > SLOT) c = SLOT;
        p.bcnt[b * 16 + t] = c;
        ic[16 + t] = 0;
    }
    __syncthreads();
    for (int e = e0 + t; e < e0 + EPB; e += 1024) {
        int cv = p.col[e];
        int r = cv / BW_;
        int k = atomicAdd(&ic[16 + r], 1);
        if (k < SLOT) {
            size_t idx = (size_t)(r * PBLK + b) * SLOT + k;
            p.bcol[idx] = cv;
            p.brow[idx] = p.row[e];
        }
    }
    // y0: 4 threads per node (4-lane groups aligned within waves)
    if (t < 4 * NB) {
        int i = b * NB + (t >> 2);
        if (i < N_) {
            int part = t & 3;
            int j0 = part * 19, j1 = j0 + 19; if (j1 > F_) j1 = F_;
            const float* xi = p.x + (size_t)i * F_;
            float s = 0.f;
            for (int j = j0; j < j1; ++j) s += xi[j] * sv[j];
            s += __shfl_xor(s, 1);
            s += __shfl_xor(s, 2);
            if (part == 0) p.u[i] = s;
        }
    } else if (b == 0) {
        int e = t - 4 * NB;          // 0..239
        float b2v = p.b2[0];
        for (int i = e; i < G_; i += 1024 - 4 * NB) p.out[i] = b2v;
        if (e < 16) p.cnt2[e] = 0;
        else if (e < 32) p.cnt3[e - 16] = 0;
        if (e == 32) {
            float s = 0.f;
            #pragma unroll 8
            for (int j = 0; j < H_; ++j) s += p.b1[j] * p.W2[j];
            p.cbw[0] = s;
        }
    }
}

// ---------- K2/K3: bucketed LDS scatter + last-block-per-range tail ----------
// HOP=0: value 1.0 (degree); tail: dis = rsqrt(1+deg), kd pack, u0 = dis*y0.
// HOP=1: value u0[row];      tail: u1 = dis^2 * (S1 + u0).
template <int HOP>
__global__ __launch_bounds__(1024)
void k_scat(Pr p) {
    const int t = threadIdx.x;
    const int c = blockIdx.x, r = blockIdx.y;
    __shared__ float bins[BW_];
    __shared__ int ic[24];
    for (int i = t; i < BW_; i += 1024) bins[i] = 0.f;
    if (t == 0) {
        int acc = 0;
        #pragma unroll
        for (int q = 0; q < 16; ++q) { ic[q] = acc; acc += p.bcnt[(c * 16 + q) * 16 + r]; }
        ic[16] = acc;
    }
    __syncthreads();
    const int T = ic[16];
    const int lo = r * BW_;
    for (int j = t; j < T; j += 1024) {
        int q = 0;
        #pragma unroll
        for (int z = 1; z < 16; ++z) if (j >= ic[z]) q = z;
        size_t idx = (size_t)(r * PBLK + c * 16 + q) * SLOT + (j - ic[q]);
        float val = HOP ? p.u[p.brow[idx]] : 1.0f;
        atomicAdd(&bins[p.bcol[idx] - lo], val);   // ds_add_f32
    }
    __syncthreads();
    {
        float* dst = p.partial + (size_t)c * N_ + lo;
        for (int i = t; i < BW_; i += 1024) dst[i] = bins[i];
    }
    __threadfence();                    // release: partial slice visible
    __syncthreads();
    if (t == 0) {
        int* cnt = HOP ? p.cnt3 : p.cnt2;
        ic[20] = (atomicAdd(&cnt[r], 1) == CP - 1);
    }
    __syncthreads();
    if (!ic[20]) return;
    __threadfence();                    // acquire: invalidate stale lines
    for (int i = t; i < BW_; i += 1024) {
        int node = lo + i;
        float s = bins[i];              // own slice still in LDS
        #pragma unroll
        for (int c2 = 0; c2 < CP; ++c2)
            if (c2 != c) s += p.partial[(size_t)c2 * N_ + node];
        if (HOP == 0) {
            float d = rsqrtf(s + 1.0f);   // +1 self-loop
            p.kd[node] = make_float2(d, __int_as_float(p.batch[node]));
            p.u[node] = d * p.u[node];    // u: y0 -> u0
        } else {
            float d = p.kd[node].x;
            p.u[node] = d * d * (s + p.u[node]);   // u: u0 -> u1
        }
    }
}

// ---------- K4: hop2 + pool (512-bin LDS hist -> out atomics) ----------
__global__ __launch_bounds__(1024)
void k4_pool(Pr p) {
    const int t = threadIdx.x, b = blockIdx.x;
    __shared__ float h[G_];
    for (int i = t; i < G_; i += 1024) h[i] = 0.f;
    __syncthreads();
    const float cb0 = p.cbw[0];
    for (int q = b * 1024 + t; q < E_ / 4; q += POOLB * 1024) {
        int4 c4 = ((const int4*)p.col)[q];
        int4 r4 = ((const int4*)p.row)[q];
        float2 k0 = p.kd[c4.x], k1 = p.kd[c4.y], k2 = p.kd[c4.z], k3 = p.kd[c4.w];
        float u0 = p.u[r4.x], u1 = p.u[r4.y], u2 = p.u[r4.z], u3 = p.u[r4.w];
        atomicAdd(&h[__float_as_int(k0.y)], k0.x * u0);
        atomicAdd(&h[__float_as_int(k1.y)], k1.x * u1);
        atomicAdd(&h[__float_as_int(k2.y)], k2.x * u2);
        atomicAdd(&h[__float_as_int(k3.y)], k3.x * u3);
    }
    {
        int nt = b * 1024 + t;
        float val = 0.f; int g = -1;
        if (nt < N_) {
            float2 k = p.kd[nt];
            val = k.x * p.u[nt] + cb0;
            g = __float_as_int(k.y);
        }
        int g0 = __shfl(g, 0), g63 = __shfl(g, 63);
        if (g0 == g63 && g0 >= 0) {     // sorted batch -> one atomic per wave
            for (int o = 32; o; o >>= 1) val += __shfl_down(val, o);
            if ((t & 63) == 0) atomicAdd(&h[g0], val);
        } else if (g >= 0) {
            atomicAdd(&h[g], val);
        }
    }
    __syncthreads();
    for (int i = t; i < G_; i += 1024)
        if (h[i] != 0.f) atomicAdd(&p.out[i], h[i]);
}

// ================= fallback (plain atomic path, proven in round 2) ==========
__global__ void f_setup(const float* W1, const float* b1, const float* W2,
                        const float* b2, float* v, float* cb) {
    int t = threadIdx.x;
    if (t < F_) {
        float s = 0.f;
        for (int j = 0; j < H_; ++j) s += W1[t * H_ + j] * W2[j];
        v[t] = s;
    } else if (t == F_) {
        float s = 0.f;
        for (int j = 0; j < H_; ++j) s += b1[j] * W2[j];
        cb[0] = s; cb[1] = b2[0];
    }
}
__global__ void f_init(float* deg, float* s, int n) {
    int i = blockIdx.x * blockDim.x + threadIdx.x;
    if (i < n) { deg[i] = 1.0f; s[i] = 0.0f; }
}
__global__ void f_deg_acc(const int* __restrict__ col, float* deg, int e) {
    int i = blockIdx.x * blockDim.x + threadIdx.x;
    if (i < e) atomicAdd(&deg[col[i]], 1.0f);
}
__global__ void f_dis(float* deg, int n) {
    int i = blockIdx.x * blockDim.x + threadIdx.x;
    if (i < n) deg[i] = rsqrtf(deg[i]);
}
__global__ void f_u0(const float* __restrict__ x, const float* __restrict__ v,
                     const float* __restrict__ dis, float* u, int n) {
    __shared__ float sv[F_];
    if (threadIdx.x < F_) sv[threadIdx.x] = v[threadIdx.x];
    __syncthreads();
    int i = blockIdx.x * blockDim.x + threadIdx.x;
    if (i < n) {
        const float* xi = x + (size_t)i * F_;
        float s = 0.f;
        for (int j = 0; j < F_; ++j) s += xi[j] * sv[j];
        u[i] = dis[i] * s;
    }
}
__global__ void f_edge(const int* __restrict__ row, const int* __restrict__ col,
                       const float* __restrict__ u, float* s, int e) {
    int i = blockIdx.x * blockDim.x + threadIdx.x;
    if (i < e) atomicAdd(&s[col[i]], u[row[i]]);
}
__global__ void f_hop_finish(const float* __restrict__ dis, float* s, float* u, int n) {
    int i = blockIdx.x * blockDim.x + threadIdx.x;
    if (i < n) { float d = dis[i]; u[i] = d * d * (s[i] + u[i]); s[i] = 0.0f; }
}
__global__ void f_out_init(const float* __restrict__ cb, float* out, int g) {
    int i = blockIdx.x * blockDim.x + threadIdx.x;
    if (i < g) out[i] = cb[1];
}
__global__ void f_pool(const int* __restrict__ batch, const float* __restrict__ dis,
                       const float* __restrict__ s, const float* __restrict__ u,
                       const float* __restrict__ cb, float* out, int n) {
    int i = blockIdx.x * blockDim.x + threadIdx.x;
    if (i < n) atomicAdd(&out[batch[i]], dis[i] * (s[i] + u[i]) + cb[0]);
}
// ============================================================================

extern "C" void kernel_launch(void* const* d_in, const int* in_sizes, int n_in,
                              void* d_out, int out_size, void* d_ws, size_t ws_size,
                              hipStream_t stream) {
    const float* x   = (const float*)d_in[0];
    const int*   ei  = (const int*)d_in[1];   // [2,E] int32 (harness converts ints)
    const int*   bat = (const int*)d_in[2];   // [N] int32, sorted
    const float* W1  = (const float*)d_in[3];
    const float* b1  = (const float*)d_in[4];
    const float* W2  = (const float*)d_in[5];
    const float* b2  = (const float*)d_in[6];
    float* out = (float*)d_out;

    float* ws = (float*)d_ws;
    Pr p;
    p.x = x; p.row = ei; p.col = ei + E_; p.batch = bat;
    p.W1 = W1; p.b1 = b1; p.W2 = W2; p.b2 = b2;
    p.u       = ws;                               // N
    p.kd      = (float2*)(ws + N_);               // 2N floats, 8B aligned
    p.partial = ws + 3 * N_;                      // CP*N
    p.bcnt    = (int*)(ws + 3 * N_ + (size_t)CP * N_);   // PBLK*16
    p.cnt2    = p.bcnt + PBLK * 16;               // 16
    p.cnt3    = p.cnt2 + 16;                      // 16
    p.cbw     = (float*)(p.cnt3 + 16);            // 8
    p.bcol    = (int*)(p.cbw + 8);                // RR*PBLK*SLOT
    p.brow    = p.bcol + (size_t)RR * PBLK * SLOT;
    p.out     = out;

    const size_t need = ((size_t)3 * N_ + (size_t)CP * N_ + PBLK * 16 + 40
                         + 2 * (size_t)RR * PBLK * SLOT) * sizeof(float);

    if (ws_size >= need) {
        k1_part<<<PBLK, 1024, 0, stream>>>(p);
        k_scat<0><<<dim3(CP, RR), 1024, 0, stream>>>(p);
        k_scat<1><<<dim3(CP, RR), 1024, 0, stream>>>(p);
        k4_pool<<<POOLB, 1024, 0, stream>>>(p);
    } else {
        // plain atomic fallback: v 128 | cb 8 | dis N | u N | s N
        float* v  = ws;
        float* cb = ws + 128;
        float* dis = ws + 136;
        float* u  = dis + N_;
        float* s  = u + N_;
        const int B = 256;
        const int gN = (N_ + B - 1) / B;
        const int gE = (E_ + B - 1) / B;
        f_setup<<<1, 128, 0, stream>>>(W1, b1, W2, b2, v, cb);
        f_init<<<gN, B, 0, stream>>>(dis, s, N_);
        f_deg_acc<<<gE, B, 0, stream>>>(ei + E_, dis, E_);
        f_dis<<<gN, B, 0, stream>>>(dis, N_);
        f_u0<<<gN, B, 0, stream>>>(x, v, dis, u, N_);
        f_edge<<<gE, B, 0, stream>>>(ei, ei + E_, u, s, E_);
        f_hop_finish<<<gN, B, 0, stream>>>(dis, s, u, N_);
        f_out_init<<<1, G_, 0, stream>>>(cb, out, G_);
        f_edge<<<gE, B, 0, stream>>>(ei, ei + E_, u, s, E_);
        f_pool<<<gN, B, 0, stream>>>(bat, dis, s, u, cb, out, N_);
    }
}

// Round 8
// 83.190 us; speedup vs baseline: 3.3716x; 3.3716x over previous
//
#include <hip/hip_runtime.h>

// SGC collapsed: out[g] = b2 + sum_{n in g}(dis_n*u1_n + b1.W2)
//                        + sum_{r->c} dis_c * u1_r          (hop2 fused w/ pool)
// v = W1@W2 (75), y0 = x.v, u0 = dis*y0, u1 = dis^2*(S1+u0), S1[c]=sum u0[r].
//
// LESSONS BAKED IN:
//  R2: global fp atomics on 800K random addrs = 16G/s wall (49us/pass).
//  R6: grid.sync ~37us each (device-scope fences) -> never.
//  R7: __threadfence per-wave = L2 wb/inv storm -> k_scat 133us. NEVER fence.
//      k1_part measured ~8us, k4_pool ~5us -> launch overhead ~1-2us/kernel.
// => 6 plain kernels, kernel boundaries as barriers, bucketed LDS scatters,
//    packed edge words ((row<<12)|rel) to halve bucket-buffer traffic.

#define N_    50000
#define E_    800000
#define G_    512
#define F_    75
#define H_    128
#define RR    16         // col ranges
#define BW_   3125       // nodes per range  (fits 12 bits)
#define SLOT  288        // per (range, partition-block) slot cap (mean 195, +6.9 sigma)
#define PBLK  256        // partition blocks
#define EPB   3125       // edges per partition block
#define CP    16         // chunk blocks per range in scatter
#define POOLB 128
#define NB    196        // nodes per K1 block (ceil(N_/256))

struct Pr {
    const float* x; const int* row; const int* col; const int* batch;
    const float* W1; const float* b1; const float* W2; const float* b2;
    float* u; float2* kd; float* partial; int* bcnt; float* cbw;
    unsigned* ebuf; float* out;
};

// ---------- K1: v (per block), partition edges (packed), y0 = x.v, init ----
__global__ __launch_bounds__(1024)
void k1_part(Pr p) {
    const int t = threadIdx.x, b = blockIdx.x;
    __shared__ float sv[F_ + 1];
    __shared__ int ic[32];
    if (t < 16) ic[t] = 0;
    if (t < F_) {
        float s = 0.f;
        #pragma unroll 8
        for (int j = 0; j < H_; ++j) s += p.W1[t * H_ + j] * p.W2[j];
        sv[t] = s;
    }
    __syncthreads();
    const int e0 = b * EPB;
    for (int e = e0 + t; e < e0 + EPB; e += 1024)
        atomicAdd(&ic[p.col[e] / BW_], 1);
    __syncthreads();
    if (t < 16) {
        int c = ic[t]; if (c > SLOT) c = SLOT;
        p.bcnt[b * 16 + t] = c;
        ic[16 + t] = 0;
    }
    __syncthreads();
    for (int e = e0 + t; e < e0 + EPB; e += 1024) {
        int cv = p.col[e];
        int r = cv / BW_;
        int k = atomicAdd(&ic[16 + r], 1);
        if (k < SLOT) {
            // packed: row (16b, <50000) << 12 | (col - r*BW_) (12b, <3125)
            p.ebuf[(size_t)(r * PBLK + b) * SLOT + k] =
                ((unsigned)p.row[e] << 12) | (unsigned)(cv - r * BW_);
        }
    }
    // y0: 4 threads per node
    if (t < 4 * NB) {
        int i = b * NB + (t >> 2);
        if (i < N_) {
            int part = t & 3;
            int j0 = part * 19, j1 = j0 + 19; if (j1 > F_) j1 = F_;
            const float* xi = p.x + (size_t)i * F_;
            float s = 0.f;
            for (int j = j0; j < j1; ++j) s += xi[j] * sv[j];
            s += __shfl_xor(s, 1);
            s += __shfl_xor(s, 2);
            if (part == 0) p.u[i] = s;
        }
    } else if (b == 0) {
        int e = t - 4 * NB;          // 0..239
        float b2v = p.b2[0];
        for (int i = e; i < G_; i += 1024 - 4 * NB) p.out[i] = b2v;
        if (e == 32) {
            float s = 0.f;
            #pragma unroll 8
            for (int j = 0; j < H_; ++j) s += p.b1[j] * p.W2[j];
            p.cbw[0] = s;
        }
    }
}

// ---------- K2/K4: bucketed LDS scatter -> dense partial slices ----------
// HOP=0: degree (+1.0 per edge).  HOP=1: += u0[packed>>12].
template <int HOP>
__global__ __launch_bounds__(1024)
void k_scat(Pr p) {
    const int t = threadIdx.x;
    const int c = blockIdx.x, r = blockIdx.y;
    __shared__ float bins[BW_];
    __shared__ int ic[20];
    for (int i = t; i < BW_; i += 1024) bins[i] = 0.f;
    if (t == 0) {
        int acc = 0;
        #pragma unroll
        for (int q = 0; q < 16; ++q) { ic[q] = acc; acc += p.bcnt[(c * 16 + q) * 16 + r]; }
        ic[16] = acc;
    }
    __syncthreads();
    const int T = ic[16];
    const unsigned* eb = p.ebuf + (size_t)r * PBLK * SLOT + (size_t)c * 16 * SLOT;
    for (int j = t; j < T; j += 1024) {
        int q = 0;
        #pragma unroll
        for (int z = 1; z < 16; ++z) if (j >= ic[z]) q = z;
        unsigned w = eb[(size_t)q * SLOT + (j - ic[q])];
        float val = HOP ? p.u[w >> 12] : 1.0f;
        atomicAdd(&bins[w & 4095u], val);   // ds_add_f32
    }
    __syncthreads();
    float* dst = p.partial + (size_t)c * N_ + r * BW_;
    for (int i = t; i < BW_; i += 1024) dst[i] = bins[i];
}

// ---------- K3: dis = rsqrt(1+deg), kd = {dis, batch}, u0 = dis*y0 ----------
__global__ __launch_bounds__(1024)
void k3_dis(Pr p) {
    int i = blockIdx.x * 1024 + threadIdx.x;
    if (i >= N_) return;
    float s = 1.0f;   // self-loop
    #pragma unroll
    for (int c = 0; c < CP; ++c) s += p.partial[(size_t)c * N_ + i];
    float d = rsqrtf(s);
    p.kd[i] = make_float2(d, __int_as_float(p.batch[i]));
    p.u[i] = d * p.u[i];
}

// ---------- K5: u1 = dis^2*(S1+u0); node-term pool into out ----------
__global__ __launch_bounds__(1024)
void k5_fin(Pr p) {
    int i = blockIdx.x * 1024 + threadIdx.x;
    float val = 0.f; int g = -1;
    if (i < N_) {
        float s = 0.f;
        #pragma unroll
        for (int c = 0; c < CP; ++c) s += p.partial[(size_t)c * N_ + i];
        float2 k = p.kd[i];
        float u1 = k.x * k.x * (s + p.u[i]);
        p.u[i] = u1;
        val = k.x * u1 + p.cbw[0];
        g = __float_as_int(k.y);
    }
    int g0 = __shfl(g, 0), g63 = __shfl(g, 63);
    if (g0 == g63 && g0 >= 0) {       // sorted batch -> one atomic per wave
        for (int o = 32; o; o >>= 1) val += __shfl_down(val, o);
        if ((threadIdx.x & 63) == 0) atomicAdd(&p.out[g0], val);
    } else if (g >= 0) {
        atomicAdd(&p.out[g], val);
    }
}

// ---------- K6: edge-term pool (int4 loads, 512-bin LDS hist) ----------
__global__ __launch_bounds__(1024)
void k6_pool(Pr p) {
    const int t = threadIdx.x, b = blockIdx.x;
    __shared__ float h[G_];
    for (int i = t; i < G_; i += 1024) h[i] = 0.f;
    __syncthreads();
    for (int q = b * 1024 + t; q < E_ / 4; q += POOLB * 1024) {
        int4 c4 = ((const int4*)p.col)[q];
        int4 r4 = ((const int4*)p.row)[q];
        float2 k0 = p.kd[c4.x], k1 = p.kd[c4.y], k2 = p.kd[c4.z], k3 = p.kd[c4.w];
        float u0 = p.u[r4.x], u1 = p.u[r4.y], u2 = p.u[r4.z], u3 = p.u[r4.w];
        atomicAdd(&h[__float_as_int(k0.y)], k0.x * u0);
        atomicAdd(&h[__float_as_int(k1.y)], k1.x * u1);
        atomicAdd(&h[__float_as_int(k2.y)], k2.x * u2);
        atomicAdd(&h[__float_as_int(k3.y)], k3.x * u3);
    }
    __syncthreads();
    for (int i = t; i < G_; i += 1024)
        if (h[i] != 0.f) atomicAdd(&p.out[i], h[i]);
}

// ================= fallback (plain atomic path, proven in round 2) ==========
__global__ void f_setup(const float* W1, const float* b1, const float* W2,
                        const float* b2, float* v, float* cb) {
    int t = threadIdx.x;
    if (t < F_) {
        float s = 0.f;
        for (int j = 0; j < H_; ++j) s += W1[t * H_ + j] * W2[j];
        v[t] = s;
    } else if (t == F_) {
        float s = 0.f;
        for (int j = 0; j < H_; ++j) s += b1[j] * W2[j];
        cb[0] = s; cb[1] = b2[0];
    }
}
__global__ void f_init(float* deg, float* s, int n) {
    int i = blockIdx.x * blockDim.x + threadIdx.x;
    if (i < n) { deg[i] = 1.0f; s[i] = 0.0f; }
}
__global__ void f_deg_acc(const int* __restrict__ col, float* deg, int e) {
    int i = blockIdx.x * blockDim.x + threadIdx.x;
    if (i < e) atomicAdd(&deg[col[i]], 1.0f);
}
__global__ void f_dis(float* deg, int n) {
    int i = blockIdx.x * blockDim.x + threadIdx.x;
    if (i < n) deg[i] = rsqrtf(deg[i]);
}
__global__ void f_u0(const float* __restrict__ x, const float* __restrict__ v,
                     const float* __restrict__ dis, float* u, int n) {
    __shared__ float sv[F_];
    if (threadIdx.x < F_) sv[threadIdx.x] = v[threadIdx.x];
    __syncthreads();
    int i = blockIdx.x * blockDim.x + threadIdx.x;
    if (i < n) {
        const float* xi = x + (size_t)i * F_;
        float s = 0.f;
        for (int j = 0; j < F_; ++j) s += xi[j] * sv[j];
        u[i] = dis[i] * s;
    }
}
__global__ void f_edge(const int* __restrict__ row, const int* __restrict__ col,
                       const float* __restrict__ u, float* s, int e) {
    int i = blockIdx.x * blockDim.x + threadIdx.x;
    if (i < e) atomicAdd(&s[col[i]], u[row[i]]);
}
__global__ void f_hop_finish(const float* __restrict__ dis, float* s, float* u, int n) {
    int i = blockIdx.x * blockDim.x + threadIdx.x;
    if (i < n) { float d = dis[i]; u[i] = d * d * (s[i] + u[i]); s[i] = 0.0f; }
}
__global__ void f_out_init(const float* __restrict__ cb, float* out, int g) {
    int i = blockIdx.x * blockDim.x + threadIdx.x;
    if (i < g) out[i] = cb[1];
}
__global__ void f_pool(const int* __restrict__ batch, const float* __restrict__ dis,
                       const float* __restrict__ s, const float* __restrict__ u,
                       const float* __restrict__ cb, float* out, int n) {
    int i = blockIdx.x * blockDim.x + threadIdx.x;
    if (i < n) atomicAdd(&out[batch[i]], dis[i] * (s[i] + u[i]) + cb[0]);
}
// ============================================================================

extern "C" void kernel_launch(void* const* d_in, const int* in_sizes, int n_in,
                              void* d_out, int out_size, void* d_ws, size_t ws_size,
                              hipStream_t stream) {
    const float* x   = (const float*)d_in[0];
    const int*   ei  = (const int*)d_in[1];   // [2,E] int32 (harness converts ints)
    const int*   bat = (const int*)d_in[2];   // [N] int32, sorted
    const float* W1  = (const float*)d_in[3];
    const float* b1  = (const float*)d_in[4];
    const float* W2  = (const float*)d_in[5];
    const float* b2  = (const float*)d_in[6];
    float* out = (float*)d_out;

    float* ws = (float*)d_ws;
    Pr p;
    p.x = x; p.row = ei; p.col = ei + E_; p.batch = bat;
    p.W1 = W1; p.b1 = b1; p.W2 = W2; p.b2 = b2;
    p.u       = ws;                                   // N
    p.kd      = (float2*)(ws + N_);                   // 2N floats (8B aligned)
    p.partial = ws + 3 * N_;                          // CP*N
    p.bcnt    = (int*)(ws + 3 * N_ + (size_t)CP * N_);// PBLK*16
    p.cbw     = (float*)(p.bcnt + PBLK * 16);         // 8
    p.ebuf    = (unsigned*)(p.cbw + 8);               // RR*PBLK*SLOT (packed)
    p.out     = out;

    const size_t need = ((size_t)3 * N_ + (size_t)CP * N_ + PBLK * 16 + 8
                         + (size_t)RR * PBLK * SLOT) * sizeof(float);

    const int gN1024 = (N_ + 1023) / 1024;

    if (ws_size >= need) {
        k1_part<<<PBLK, 1024, 0, stream>>>(p);
        k_scat<0><<<dim3(CP, RR), 1024, 0, stream>>>(p);
        k3_dis<<<gN1024, 1024, 0, stream>>>(p);
        k_scat<1><<<dim3(CP, RR), 1024, 0, stream>>>(p);
        k5_fin<<<gN1024, 1024, 0, stream>>>(p);
        k6_pool<<<POOLB, 1024, 0, stream>>>(p);
    } else {
        // plain atomic fallback: v 128 | cb 8 | dis N | u N | s N
        float* v  = ws;
        float* cb = ws + 128;
        float* dis = ws + 136;
        float* u  = dis + N_;
        float* s  = u + N_;
        const int B = 256;
        const int gN = (N_ + B - 1) / B;
        const int gE = (E_ + B - 1) / B;
        f_setup<<<1, 128, 0, stream>>>(W1, b1, W2, b2, v, cb);
        f_init<<<gN, B, 0, stream>>>(dis, s, N_);
        f_deg_acc<<<gE, B, 0, stream>>>(ei + E_, dis, E_);
        f_dis<<<gN, B, 0, stream>>>(dis, N_);
        f_u0<<<gN, B, 0, stream>>>(x, v, dis, u, N_);
        f_edge<<<gE, B, 0, stream>>>(ei, ei + E_, u, s, E_);
        f_hop_finish<<<gN, B, 0, stream>>>(dis, s, u, N_);
        f_out_init<<<1, G_, 0, stream>>>(cb, out, G_);
        f_edge<<<gE, B, 0, stream>>>(ei, ei + E_, u, s, E_);
        f_pool<<<gN, B, 0, stream>>>(bat, dis, s, u, cb, out, N_);
    }
}